// Round 18
// baseline (188.386 us; speedup 1.0000x reference)
//
#include <hip/hip_runtime.h>

// Trajectron sliding-window LSTM embed:
//   inputs [T=256, B=128, N=4, D=2] f32
//   his LSTM H=32 over n=3; int LSTM H=8 over n=0; window 64 ending at t
//   out[t,b,:] = [h_his | h_int] @ W_out.T + b_out   -> [256,128,2] f32
//
// Round-30 (two jobs per wave): R29's counters fit a precise model:
// per-step issue ~1560 cy, step time ~4220 cy -> single-wave duty 0.37;
// duration = 64 x step-latency regardless of occupancy (R27/28 proved
// more waves don't shorten a wave's step; R24/26 proved the compiler
// won't pipeline across the backedge). The only lever left is step time.
// Fix: each wave runs TWO independent window-jobs (b and b+772), their
// per-step sections interleaved in program order (MFMA1, MFMA2, acts1,
// acts2) so job2's ready instructions issue while job1's chain stalls --
// in-order issue + deliberate ordering = manual latency hiding. Weights
// (A-frags, 72 VGPR) are shared; only states duplicate. 772 blocks.
// Job pairing: id1 = b (j1 = b>>3 in 0..96), id2 = b+772 (j2 in 96..192);
// every (window j, chain-group bg) covered exactly once; b<8 are prefix
// blocks (readout every step -> t=0..63, verified R29 path).
// Per-job math byte-identical to verified R23/R29 (absmax 4.88e-4).

typedef float v4f __attribute__((ext_vector_type(4)));
typedef _Float16 h8v __attribute__((ext_vector_type(8)));

static __device__ __forceinline__ float fexp2(float x) {
    return __builtin_amdgcn_exp2f(x);
}
static __device__ __forceinline__ float frcp(float x) {
    return __builtin_amdgcn_rcpf(x);
}
static __device__ __forceinline__ unsigned short f2h(float f) {
    _Float16 h = (_Float16)f;
    unsigned short u;
    __builtin_memcpy(&u, &h, 2);
    return u;
}
static __device__ __forceinline__ float h2f(unsigned short u) {
    _Float16 h;
    __builtin_memcpy(&h, &u, 2);
    return (float)h;
}

#define LOG2E    1.442695041f
#define TWOLOG2E 2.885390082f
#define H16ONE   0x3C00u

// 7-trans LSTM unit update (5 exp2 + 2 rcp).
static __device__ __forceinline__ void lstm_unit(
    float Di, float Df, float Dg, float Do, float& c, float& h)
{
    const float ei = fminf(fexp2(Di), 1e12f);
    const float ef = fminf(fexp2(Df), 1e12f);
    const float eg = fminf(fexp2(Dg), 1e12f);
    const float eo = fminf(fexp2(Do), 1e18f);
    const float pi1 = 1.f + ei, pf1 = 1.f + ef, pg1 = 1.f + eg;
    const float p12 = pi1 * pg1;                  // (1+ei)(1+eg)
    const float r3  = frcp(p12 * pf1);            // <= 1e36, no INF
    const float cn  = fmaf(p12, c, (1.f - eg) * pf1) * r3;
    c = cn;
    const float ec = fminf(fexp2(TWOLOG2E * cn), 1e18f);
    h = (ec - 1.f) * frcp((1.f + eo) * (1.f + ec));
}

// projection + store: his units q*8..+7 in hH, int units {2q,2q+1}
static __device__ __forceinline__ void project_store(
    const float* __restrict__ W_out, const float* __restrict__ b_out,
    float* __restrict__ out, const float hH[8], float ih0, float ih1,
    int q, int lane, int outIdx)
{
    float e0 = fmaf(W_out[33 + 2 * q], ih1, W_out[32 + 2 * q] * ih0);
    float e1 = fmaf(W_out[73 + 2 * q], ih1, W_out[72 + 2 * q] * ih0);
#pragma unroll
    for (int r = 0; r < 4; ++r) {
        e0 = fmaf(W_out[q * 8 + r], hH[r],
                  fmaf(W_out[q * 8 + 4 + r], hH[4 + r], e0));
        e1 = fmaf(W_out[40 + q * 8 + r], hH[r],
                  fmaf(W_out[44 + q * 8 + r], hH[4 + r], e1));
    }
    e0 += __shfl_xor(e0, 16); e1 += __shfl_xor(e1, 16);
    e0 += __shfl_xor(e0, 32); e1 += __shfl_xor(e1, 32);
    if (lane < 16) {
        float2 o;
        o.x = e0 + b_out[0];
        o.y = e1 + b_out[1];
        reinterpret_cast<float2*>(out)[outIdx] = o;
    }
}

// ws layout:
//   ushort [0,4096)     hisAW : A-frags WhhP his, [T=8][n=16][k=32]
//   ushort [4096,8192)  hisAX : A-frags x-part his (k<8 used), [8][16][32]
//   ushort [8192,9216)  intAW : A-frags int (Whh+Wih+b in K-slots), [2][16][32]
// his perm: row p = T*16 + m: gate g = T>>1,
//   unit u = (m>>2)*8 + 4*(T&1) + (m&3), orig = g*32+u
// int perm: row p = T*16 + m: gate g = 2T + ((m&3)>>1),
//   unit u = 2*(m>>2) + (m&1), orig = g*8+u
// scale s = -log2e (i,f,o gates) / -2log2e (g gate)
__global__ __launch_bounds__(256) void prep_kernel(
    const float* __restrict__ Wih_his, const float* __restrict__ Whh_his,
    const float* __restrict__ bih_his, const float* __restrict__ bhh_his,
    const float* __restrict__ Wih_int, const float* __restrict__ Whh_int,
    const float* __restrict__ bih_int, const float* __restrict__ bhh_int,
    float* __restrict__ ws)
{
    const int i = blockIdx.x * 256 + threadIdx.x;
    unsigned short* wsu = reinterpret_cast<unsigned short*>(ws);

    if (i < 4096) {                     // hisAW: Whh part
        const int T = i >> 9, m = (i >> 5) & 15, k = i & 31;
        const int g = T >> 1;
        const int u = ((m >> 2) << 3) + ((T & 1) << 2) + (m & 3);
        const int orig = g * 32 + u;
        const float s = (g == 2) ? -TWOLOG2E : -LOG2E;
        wsu[i] = f2h(Whh_his[orig * 32 + k] * s);
    } else if (i < 8192) {              // hisAX: x-part (hi/lo exact)
        const int e = i - 4096;
        const int T = e >> 9, m = (e >> 5) & 15, k = e & 31;
        const int g = T >> 1;
        const int u = ((m >> 2) << 3) + ((T & 1) << 2) + (m & 3);
        const int orig = g * 32 + u;
        const float s = (g == 2) ? -TWOLOG2E : -LOG2E;
        const float w0 = Wih_his[orig * 2] * s;
        const float w1 = Wih_his[orig * 2 + 1] * s;
        const float b  = (bih_his[orig] + bhh_his[orig]) * s;
        unsigned short v = 0;
        switch (k) {
            case 0: v = f2h(w0); break;
            case 1: v = f2h(w1); break;
            case 2: v = f2h(b);  break;
            case 3: v = f2h(w0 - h2f(f2h(w0))); break;
            case 4: v = f2h(w1 - h2f(f2h(w1))); break;
            case 5: v = f2h(b  - h2f(f2h(b)));  break;
            case 6: v = f2h(w0); break;
            case 7: v = f2h(w1); break;
            default: v = 0; break;
        }
        wsu[4096 + e] = v;
    } else if (i < 9216) {              // intAW: Whh + Wih + b in K-slots
        const int e = i - 8192;
        const int T = e >> 9, m = (e >> 5) & 15, k = e & 31;
        const int q = k >> 3, j = k & 7;
        const int g = 2 * T + ((m & 3) >> 1);
        const int u = 2 * (m >> 2) + (m & 1);
        const int orig = g * 8 + u;
        const float s = (g == 2) ? -TWOLOG2E : -LOG2E;
        unsigned short v = 0;
        if (j < 6) {
            const int col = 2 * q + (j & 1);
            const float w = Whh_int[orig * 8 + col] * s;
            v = (j == 2 || j == 3) ? f2h(w - h2f(f2h(w))) : f2h(w);
        } else {
            const int comp = j & 1;
            if (q <= 1) {                       // w_hi . xh / w_hi . xl
                v = f2h(Wih_int[orig * 2 + comp] * s);
            } else if (q == 2) {                // w_lo . xh
                const float w = Wih_int[orig * 2 + comp] * s;
                v = f2h(w - h2f(f2h(w)));
            } else {                            // bias hi / lo
                const float b = (bih_int[orig] + bhh_int[orig]) * s;
                v = (comp == 0) ? f2h(b) : f2h(b - h2f(f2h(b)));
            }
        }
        wsu[8192 + e] = v;
    }
}

// ---------- fused his+int LSTM: 1 wave, TWO independent window-jobs ------
__global__ __launch_bounds__(64, 1) void fusedp_kernel(
    const float* __restrict__ inp, const float* __restrict__ ws,
    const float* __restrict__ W_out, const float* __restrict__ b_out,
    float* __restrict__ out)
{
    const int lane = threadIdx.x;
    const int n    = lane & 15;
    const int q    = lane >> 4;
    const int b    = blockIdx.x;               // 0..771
    const int id2  = b + 772;
    const int j1   = b >> 3,  bg1 = b & 7;     // j1 in 0..96
    const int j2   = id2 >> 3, bg2 = id2 & 7;  // j2 in 96..192
    const bool readout = (j1 == 0);            // b < 8: prefix block

    const unsigned short* wsu = reinterpret_cast<const unsigned short*>(ws);
    const h8v* wa = reinterpret_cast<const h8v*>(wsu);          // hisAW
    const h8v* wx = reinterpret_cast<const h8v*>(wsu + 4096);   // hisAX
    const h8v* wi = reinterpret_cast<const h8v*>(wsu + 8192);   // intAW
    h8v AW[8], AX[8], AI[2];
#pragma unroll
    for (int T = 0; T < 8; ++T) {
        AW[T] = wa[T * 64 + n * 4 + q];
        AX[T] = wx[T * 64 + n * 4 + q];
    }
#pragma unroll
    for (int T = 0; T < 2; ++T) AI[T] = wi[T * 64 + n * 4 + q];

    const int chain1 = bg1 * 16 + n;
    const int chain2 = bg2 * 16 + n;
    const float* xb1 = inp + chain1 * 8;
    const float* xb2 = inp + chain2 * 8;
    float2 xvH1 = *reinterpret_cast<const float2*>(xb1 + j1 * 1024 + 6);
    float2 xvI1 = *reinterpret_cast<const float2*>(xb1 + j1 * 1024);
    float2 xvH2 = *reinterpret_cast<const float2*>(xb2 + j2 * 1024 + 6);
    float2 xvI2 = *reinterpret_cast<const float2*>(xb2 + j2 * 1024);

    union BU { unsigned u[4]; h8v h; };
    BU bhH1; bhH1.u[0] = bhH1.u[1] = bhH1.u[2] = bhH1.u[3] = 0;
    BU bhI1; bhI1.u[0] = bhI1.u[1] = bhI1.u[2] = bhI1.u[3] = 0;
    BU bhH2; bhH2.u[0] = bhH2.u[1] = bhH2.u[2] = bhH2.u[3] = 0;
    BU bhI2; bhI2.u[0] = bhI2.u[1] = bhI2.u[2] = bhI2.u[3] = 0;
    float cH1[8] = {0.f, 0.f, 0.f, 0.f, 0.f, 0.f, 0.f, 0.f};
    float hH1[8] = {0.f, 0.f, 0.f, 0.f, 0.f, 0.f, 0.f, 0.f};
    float cH2[8] = {0.f, 0.f, 0.f, 0.f, 0.f, 0.f, 0.f, 0.f};
    float hH2[8] = {0.f, 0.f, 0.f, 0.f, 0.f, 0.f, 0.f, 0.f};
    float cI01 = 0.f, cI11 = 0.f, ih01 = 0.f, ih11 = 0.f;
    float cI02 = 0.f, cI12 = 0.f, ih02 = 0.f, ih12 = 0.f;

#pragma unroll 1
    for (int s = 0; s < 64; ++s) {
        // branch-free prefetch for both jobs (last iter's value dead)
        const int sn = (s < 63) ? (s + 1) : 63;
        const float* xr1 = xb1 + (j1 + sn) * 1024;
        const float* xr2 = xb2 + (j2 + sn) * 1024;
        const float2 xnH1 = *reinterpret_cast<const float2*>(xr1 + 6);
        const float2 xnI1 = *reinterpret_cast<const float2*>(xr1);
        const float2 xnH2 = *reinterpret_cast<const float2*>(xr2 + 6);
        const float2 xnI2 = *reinterpret_cast<const float2*>(xr2);

        // -------- x builds (both jobs) --------
        BU bx1, bx2;
        {
            const unsigned short xh = f2h(xvH1.x), yh = f2h(xvH1.y);
            const unsigned short xl = f2h(xvH1.x - h2f(xh));
            const unsigned short yl = f2h(xvH1.y - h2f(yh));
            bx1.u[0] = ((unsigned)yh << 16) | xh;
            bx1.u[1] = ((unsigned)xh << 16) | H16ONE;
            bx1.u[2] = (H16ONE << 16) | yh;
            bx1.u[3] = ((unsigned)yl << 16) | xl;
            if (q != 0) { bx1.u[0] = 0; bx1.u[1] = 0; bx1.u[2] = 0; bx1.u[3] = 0; }
        }
        {
            const unsigned short xh = f2h(xvH2.x), yh = f2h(xvH2.y);
            const unsigned short xl = f2h(xvH2.x - h2f(xh));
            const unsigned short yl = f2h(xvH2.y - h2f(yh));
            bx2.u[0] = ((unsigned)yh << 16) | xh;
            bx2.u[1] = ((unsigned)xh << 16) | H16ONE;
            bx2.u[2] = (H16ONE << 16) | yh;
            bx2.u[3] = ((unsigned)yl << 16) | xl;
            if (q != 0) { bx2.u[0] = 0; bx2.u[1] = 0; bx2.u[2] = 0; bx2.u[3] = 0; }
        }
        {
            const unsigned short xh = f2h(xvI1.x), yh = f2h(xvI1.y);
            const unsigned short xl = f2h(xvI1.x - h2f(xh));
            const unsigned short yl = f2h(xvI1.y - h2f(yh));
            const unsigned ph = ((unsigned)yh << 16) | xh;
            const unsigned pl = ((unsigned)yl << 16) | xl;
            bhI1.u[3] = (q == 3) ? ((H16ONE << 16) | H16ONE)
                                 : ((q == 1) ? pl : ph);
        }
        {
            const unsigned short xh = f2h(xvI2.x), yh = f2h(xvI2.y);
            const unsigned short xl = f2h(xvI2.x - h2f(xh));
            const unsigned short yl = f2h(xvI2.y - h2f(yh));
            const unsigned ph = ((unsigned)yh << 16) | xh;
            const unsigned pl = ((unsigned)yl << 16) | xl;
            bhI2.u[3] = (q == 3) ? ((H16ONE << 16) | H16ONE)
                                 : ((q == 1) ? pl : ph);
        }

        const v4f z = {0.f, 0.f, 0.f, 0.f};

        // -------- MFMAs: int both jobs, then his job1, his job2 --------
        const v4f E10 = __builtin_amdgcn_mfma_f32_16x16x32_f16(AI[0], bhI1.h, z, 0, 0, 0);
        const v4f E11 = __builtin_amdgcn_mfma_f32_16x16x32_f16(AI[1], bhI1.h, z, 0, 0, 0);
        const v4f E20 = __builtin_amdgcn_mfma_f32_16x16x32_f16(AI[0], bhI2.h, z, 0, 0, 0);
        const v4f E21 = __builtin_amdgcn_mfma_f32_16x16x32_f16(AI[1], bhI2.h, z, 0, 0, 0);

        v4f D1[8], D2[8];
#pragma unroll
        for (int T = 0; T < 8; ++T) {
            const v4f cx = __builtin_amdgcn_mfma_f32_16x16x32_f16(AX[T], bx1.h, z, 0, 0, 0);
            D1[T] = __builtin_amdgcn_mfma_f32_16x16x32_f16(AW[T], bhH1.h, cx, 0, 0, 0);
        }
#pragma unroll
        for (int T = 0; T < 8; ++T) {
            const v4f cx = __builtin_amdgcn_mfma_f32_16x16x32_f16(AX[T], bx2.h, z, 0, 0, 0);
            D2[T] = __builtin_amdgcn_mfma_f32_16x16x32_f16(AW[T], bhH2.h, cx, 0, 0, 0);
        }

        // -------- int activations (E ready first) --------
        lstm_unit(E10[0], E10[2], E11[0], E11[2], cI01, ih01);
        lstm_unit(E10[1], E10[3], E11[1], E11[3], cI11, ih11);
        {
            const unsigned short hh0 = f2h(ih01), hh1 = f2h(ih11);
            const unsigned short hl0 = f2h(ih01 - h2f(hh0));
            const unsigned short hl1 = f2h(ih11 - h2f(hh1));
            bhI1.u[0] = ((unsigned)hh1 << 16) | hh0;
            bhI1.u[1] = bhI1.u[0];
            bhI1.u[2] = ((unsigned)hl1 << 16) | hl0;
        }
        lstm_unit(E20[0], E20[2], E21[0], E21[2], cI02, ih02);
        lstm_unit(E20[1], E20[3], E21[1], E21[3], cI12, ih12);
        {
            const unsigned short hh0 = f2h(ih02), hh1 = f2h(ih12);
            const unsigned short hl0 = f2h(ih02 - h2f(hh0));
            const unsigned short hl1 = f2h(ih12 - h2f(hh1));
            bhI2.u[0] = ((unsigned)hh1 << 16) | hh0;
            bhI2.u[1] = bhI2.u[0];
            bhI2.u[2] = ((unsigned)hl1 << 16) | hl0;
        }

        // -------- his activations job1, then job2 --------
#pragma unroll
        for (int hi = 0; hi < 2; ++hi)
#pragma unroll
            for (int lo = 0; lo < 4; ++lo) {
                const int ww = hi * 4 + lo;
                lstm_unit(D1[hi][lo], D1[2 + hi][lo], D1[4 + hi][lo],
                          D1[6 + hi][lo], cH1[ww], hH1[ww]);
            }
#pragma unroll
        for (int d = 0; d < 4; ++d)
            bhH1.u[d] = ((unsigned)f2h(hH1[2 * d + 1]) << 16) | f2h(hH1[2 * d]);

#pragma unroll
        for (int hi = 0; hi < 2; ++hi)
#pragma unroll
            for (int lo = 0; lo < 4; ++lo) {
                const int ww = hi * 4 + lo;
                lstm_unit(D2[hi][lo], D2[2 + hi][lo], D2[4 + hi][lo],
                          D2[6 + hi][lo], cH2[ww], hH2[ww]);
            }
#pragma unroll
        for (int d = 0; d < 4; ++d)
            bhH2.u[d] = ((unsigned)f2h(hH2[2 * d + 1]) << 16) | f2h(hH2[2 * d]);

        // -------- prefix readout (job1 only; 8 of 772 blocks) --------
        if (readout)
            project_store(W_out, b_out, out, hH1, ih01, ih11,
                          q, lane, s * 128 + chain1);

        xvH1 = xnH1; xvI1 = xnI1;
        xvH2 = xnH2; xvI2 = xnI2;
    }

    // ---- epilogue: job1 (full blocks) + job2 (always full) --------------
    if (!readout)
        project_store(W_out, b_out, out, hH1, ih01, ih11,
                      q, lane, (63 + j1) * 128 + chain1);
    project_store(W_out, b_out, out, hH2, ih02, ih12,
                  q, lane, (63 + j2) * 128 + chain2);
}

extern "C" void kernel_launch(void* const* d_in, const int* in_sizes, int n_in,
                              void* d_out, int out_size, void* d_ws, size_t ws_size,
                              hipStream_t stream) {
    const float* inp     = (const float*)d_in[0];
    const float* Wih_his = (const float*)d_in[1];
    const float* Whh_his = (const float*)d_in[2];
    const float* bih_his = (const float*)d_in[3];
    const float* bhh_his = (const float*)d_in[4];
    const float* Wih_int = (const float*)d_in[5];
    const float* Whh_int = (const float*)d_in[6];
    const float* bih_int = (const float*)d_in[7];
    const float* bhh_int = (const float*)d_in[8];
    const float* W_out   = (const float*)d_in[9];
    const float* b_out   = (const float*)d_in[10];
    float* out  = (float*)d_out;
    float* ws   = (float*)d_ws;

    // pre-pass: build permuted fp16 A-frag tables (hi/lo exact splits)
    prep_kernel<<<dim3(36), dim3(256), 0, stream>>>(
        Wih_his, Whh_his, bih_his, bhh_his,
        Wih_int, Whh_int, bih_int, bhh_int, ws);

    // fused his+int LSTM: 772 blocks, each wave runs TWO window-jobs
    fusedp_kernel<<<dim3(772), dim3(64), 0, stream>>>(
        inp, ws, W_out, b_out, out);
}

// Round 19
// 188.380 us; speedup vs baseline: 1.0000x; 1.0000x over previous
//
#include <hip/hip_runtime.h>

// Trajectron sliding-window LSTM embed:
//   inputs [T=256, B=128, N=4, D=2] f32
//   his LSTM H=32 over n=3; int LSTM H=8 over n=0; window 64 ending at t
//   out[t,b,:] = [h_his | h_int] @ W_out.T + b_out   -> [256,128,2] f32
//
// Round-31 (2 waves x 2 jobs): R30 proved in-wave 2-job ILP works (per-job
// step-latency 4220 -> 2357 cy, duty 0.37 -> 0.66) but 772 one-wave blocks
// underfilled the machine (0.75 waves/SIMD, VALUBusy 51%). R27/28 proved
// unit-splitting fills SIMDs but 1 chain/wave gives low duty. This round
// takes the untried cell: 772 blocks x 2 waves; wave w owns units
// w*16..+15 of BOTH paired jobs (A = b, B = b+772). Per-wave issue is
// unchanged (~1560 cy: 8 his MFMA-pairs + 2 int MFMA + 70 trans) but each
// wave has TWO independent chains (duty ~0.66) AND 1544 waves = 1.5/SIMD.
// h-exchange: R27's verified LDS layout ([16 ch][80 B], double-buffered,
// one __syncthreads/step) x 2 jobs. Weights: R27's verified unit-split
// prep (row (w*4+Tl)*16+m <-> orig Tl*32+w*16+m). int jobs: wave0 runs
// A's, wave1 runs B's (balanced; AI frags identical in both waves).
// b<8 are prefix blocks (jA=0): per-step readout of job A via ebuf
// (R28's verified in-loop pattern). Numerics: same fp16 products/packing
// as R27/R28/R29 -> absmax ~4.88e-4.

typedef float v4f __attribute__((ext_vector_type(4)));
typedef _Float16 h8v __attribute__((ext_vector_type(8)));

static __device__ __forceinline__ float fexp2(float x) {
    return __builtin_amdgcn_exp2f(x);
}
static __device__ __forceinline__ float frcp(float x) {
    return __builtin_amdgcn_rcpf(x);
}
static __device__ __forceinline__ unsigned short f2h(float f) {
    _Float16 h = (_Float16)f;
    unsigned short u;
    __builtin_memcpy(&u, &h, 2);
    return u;
}
static __device__ __forceinline__ float h2f(unsigned short u) {
    _Float16 h;
    __builtin_memcpy(&h, &u, 2);
    return (float)h;
}

#define LOG2E    1.442695041f
#define TWOLOG2E 2.885390082f
#define H16ONE   0x3C00u

// 7-trans LSTM unit update (5 exp2 + 2 rcp).
static __device__ __forceinline__ void lstm_unit(
    float Di, float Df, float Dg, float Do, float& c, float& h)
{
    const float ei = fminf(fexp2(Di), 1e12f);
    const float ef = fminf(fexp2(Df), 1e12f);
    const float eg = fminf(fexp2(Dg), 1e12f);
    const float eo = fminf(fexp2(Do), 1e18f);
    const float pi1 = 1.f + ei, pf1 = 1.f + ef, pg1 = 1.f + eg;
    const float p12 = pi1 * pg1;                  // (1+ei)(1+eg)
    const float r3  = frcp(p12 * pf1);            // <= 1e36, no INF
    const float cn  = fmaf(p12, c, (1.f - eg) * pf1) * r3;
    c = cn;
    const float ec = fminf(fexp2(TWOLOG2E * cn), 1e18f);
    h = (ec - 1.f) * frcp((1.f + eo) * (1.f + ec));
}

// partial projection over this wave's 4 his units (u0 = w*16+q*4)
static __device__ __forceinline__ void his_partial(
    const float* __restrict__ W_out, const float hH[4], int u0,
    float& e0, float& e1)
{
#pragma unroll
    for (int r = 0; r < 4; ++r) {
        e0 = fmaf(W_out[u0 + r],      hH[r], e0);
        e1 = fmaf(W_out[40 + u0 + r], hH[r], e1);
    }
}

// ws layout (R27 unit-split):
//   ushort [0,4096)     hisAW : [w*4+Tl][m][k=32] fp16, orig row
//                       Tl*32 + w*16 + m, scale by gate Tl
//   ushort [4096,8192)  hisAX : same rows, x-part in k<8 slots
//   ushort [8192,9216)  intAW : A-frags int (Whh+Wih+b in K-slots), [2][16][32]
// int perm: row p = T*16 + m: gate g = 2T + ((m&3)>>1),
//   unit u = 2*(m>>2) + (m&1), orig = g*8+u
// scale s = -log2e (i,f,o gates) / -2log2e (g gate)
__global__ __launch_bounds__(256) void prep_kernel(
    const float* __restrict__ Wih_his, const float* __restrict__ Whh_his,
    const float* __restrict__ bih_his, const float* __restrict__ bhh_his,
    const float* __restrict__ Wih_int, const float* __restrict__ Whh_int,
    const float* __restrict__ bih_int, const float* __restrict__ bhh_int,
    float* __restrict__ ws)
{
    const int i = blockIdx.x * 256 + threadIdx.x;
    unsigned short* wsu = reinterpret_cast<unsigned short*>(ws);

    if (i < 4096) {                     // hisAW: Whh part
        const int T8 = i >> 9, m = (i >> 5) & 15, k = i & 31;
        const int w = T8 >> 2, Tl = T8 & 3;
        const int orig = Tl * 32 + w * 16 + m;
        const float s = (Tl == 2) ? -TWOLOG2E : -LOG2E;
        wsu[i] = f2h(Whh_his[orig * 32 + k] * s);
    } else if (i < 8192) {              // hisAX: x-part (hi/lo exact)
        const int e = i - 4096;
        const int T8 = e >> 9, m = (e >> 5) & 15, k = e & 31;
        const int w = T8 >> 2, Tl = T8 & 3;
        const int orig = Tl * 32 + w * 16 + m;
        const float s = (Tl == 2) ? -TWOLOG2E : -LOG2E;
        const float w0 = Wih_his[orig * 2] * s;
        const float w1 = Wih_his[orig * 2 + 1] * s;
        const float b  = (bih_his[orig] + bhh_his[orig]) * s;
        unsigned short v = 0;
        switch (k) {
            case 0: v = f2h(w0); break;
            case 1: v = f2h(w1); break;
            case 2: v = f2h(b);  break;
            case 3: v = f2h(w0 - h2f(f2h(w0))); break;
            case 4: v = f2h(w1 - h2f(f2h(w1))); break;
            case 5: v = f2h(b  - h2f(f2h(b)));  break;
            case 6: v = f2h(w0); break;
            case 7: v = f2h(w1); break;
            default: v = 0; break;
        }
        wsu[4096 + e] = v;
    } else if (i < 9216) {              // intAW: Whh + Wih + b in K-slots
        const int e = i - 8192;
        const int T = e >> 9, m = (e >> 5) & 15, k = e & 31;
        const int q = k >> 3, j = k & 7;
        const int g = 2 * T + ((m & 3) >> 1);
        const int u = 2 * (m >> 2) + (m & 1);
        const int orig = g * 8 + u;
        const float s = (g == 2) ? -TWOLOG2E : -LOG2E;
        unsigned short v = 0;
        if (j < 6) {
            const int col = 2 * q + (j & 1);
            const float w = Whh_int[orig * 8 + col] * s;
            v = (j == 2 || j == 3) ? f2h(w - h2f(f2h(w))) : f2h(w);
        } else {
            const int comp = j & 1;
            if (q <= 1) {                       // w_hi . xh / w_hi . xl
                v = f2h(Wih_int[orig * 2 + comp] * s);
            } else if (q == 2) {                // w_lo . xh
                const float w = Wih_int[orig * 2 + comp] * s;
                v = f2h(w - h2f(f2h(w)));
            } else {                            // bias hi / lo
                const float b = (bih_int[orig] + bhh_int[orig]) * s;
                v = (comp == 0) ? f2h(b) : f2h(b - h2f(f2h(b)));
            }
        }
        wsu[8192 + e] = v;
    }
}

// ---------- fused his+int LSTM: 2 waves/block, each wave half-units of
// BOTH paired jobs (A = b, B = b+772). 18 MFMA + 70 trans per wave-step.
__global__ __launch_bounds__(128) void fusedq_kernel(
    const float* __restrict__ inp, const float* __restrict__ ws,
    const float* __restrict__ W_out, const float* __restrict__ b_out,
    float* __restrict__ out)
{
    __shared__ __align__(16) unsigned char hb[2][2][1280]; // [dbuf][job][16ch x 80B]
    __shared__ __align__(8) float2 ebuf[2][16];

    const int tid  = threadIdx.x;
    const int w    = tid >> 6;                 // wave 0/1
    const int lane = tid & 63;
    const int n    = lane & 15;
    const int q    = lane >> 4;
    const int b    = blockIdx.x;               // 0..771
    const int jA   = b >> 3,        bgA = b & 7;         // jA in 0..96
    const int idB  = b + 772;
    const int jB   = idB >> 3,      bgB = idB & 7;       // jB in 96..192
    const bool readout = (jA == 0);            // b < 8

    const unsigned short* wsu = reinterpret_cast<const unsigned short*>(ws);
    const h8v* wa = reinterpret_cast<const h8v*>(wsu);          // hisAW
    const h8v* wx = reinterpret_cast<const h8v*>(wsu + 4096);   // hisAX
    const h8v* wi = reinterpret_cast<const h8v*>(wsu + 8192);   // intAW
    h8v AW[4], AX[4], AI[2];
#pragma unroll
    for (int Tl = 0; Tl < 4; ++Tl) {
        AW[Tl] = wa[(w * 4 + Tl) * 64 + n * 4 + q];
        AX[Tl] = wx[(w * 4 + Tl) * 64 + n * 4 + q];
    }
#pragma unroll
    for (int T = 0; T < 2; ++T) AI[T] = wi[T * 64 + n * 4 + q];

    const int chainA = bgA * 16 + n;
    const int chainB = bgB * 16 + n;
    const float* xbA = inp + chainA * 8;
    const float* xbB = inp + chainB * 8;
    float2 xvHA = *reinterpret_cast<const float2*>(xbA + jA * 1024 + 6);
    float2 xvHB = *reinterpret_cast<const float2*>(xbB + jB * 1024 + 6);
    // int job: wave0 -> A, wave1 -> B
    const float* xbI = (w == 0) ? xbA : xbB;
    const int    jI  = (w == 0) ? jA  : jB;
    float2 xvI = *reinterpret_cast<const float2*>(xbI + jI * 1024);

    union BU { unsigned u[4]; h8v h; };
    BU bhA; bhA.u[0] = bhA.u[1] = bhA.u[2] = bhA.u[3] = 0;
    BU bhB; bhB.u[0] = bhB.u[1] = bhB.u[2] = bhB.u[3] = 0;
    BU bhI; bhI.u[0] = bhI.u[1] = bhI.u[2] = bhI.u[3] = 0;
    float cHA[4] = {0.f, 0.f, 0.f, 0.f}, hHA[4] = {0.f, 0.f, 0.f, 0.f};
    float cHB[4] = {0.f, 0.f, 0.f, 0.f}, hHB[4] = {0.f, 0.f, 0.f, 0.f};
    float cI0 = 0.f, cI1 = 0.f, ih0 = 0.f, ih1 = 0.f;

    const int wb = n * 80 + w * 32 + q * 8;    // write: my 4 units
    const int rb = n * 80 + q * 16;            // read: my 8 B-slot units

#pragma unroll 1
    for (int s = 0; s < 64; ++s) {
        // branch-free prefetch (last iteration's value is dead; row <= 255)
        const int sn = (s < 63) ? (s + 1) : 63;
        const float2 xnHA = *reinterpret_cast<const float2*>(xbA + (jA + sn) * 1024 + 6);
        const float2 xnHB = *reinterpret_cast<const float2*>(xbB + (jB + sn) * 1024 + 6);
        const float2 xnI  = *reinterpret_cast<const float2*>(xbI + (jI + sn) * 1024);

        // his Bx builds: q0 lanes carry [xh,yh,1,xh,yh,1,xl,yl]; others 0
        BU bxA, bxB;
        {
            const unsigned short xh = f2h(xvHA.x), yh = f2h(xvHA.y);
            const unsigned short xl = f2h(xvHA.x - h2f(xh));
            const unsigned short yl = f2h(xvHA.y - h2f(yh));
            bxA.u[0] = ((unsigned)yh << 16) | xh;
            bxA.u[1] = ((unsigned)xh << 16) | H16ONE;
            bxA.u[2] = (H16ONE << 16) | yh;
            bxA.u[3] = ((unsigned)yl << 16) | xl;
            if (q != 0) { bxA.u[0] = 0; bxA.u[1] = 0; bxA.u[2] = 0; bxA.u[3] = 0; }
        }
        {
            const unsigned short xh = f2h(xvHB.x), yh = f2h(xvHB.y);
            const unsigned short xl = f2h(xvHB.x - h2f(xh));
            const unsigned short yl = f2h(xvHB.y - h2f(yh));
            bxB.u[0] = ((unsigned)yh << 16) | xh;
            bxB.u[1] = ((unsigned)xh << 16) | H16ONE;
            bxB.u[2] = (H16ONE << 16) | yh;
            bxB.u[3] = ((unsigned)yl << 16) | xl;
            if (q != 0) { bxB.u[0] = 0; bxB.u[1] = 0; bxB.u[2] = 0; bxB.u[3] = 0; }
        }
        // int B x-slot (own job): q0/q2 -> (xh,yh); q1 -> (xl,yl); q3 -> (1,1)
        {
            const unsigned short xh = f2h(xvI.x), yh = f2h(xvI.y);
            const unsigned short xl = f2h(xvI.x - h2f(xh));
            const unsigned short yl = f2h(xvI.y - h2f(yh));
            const unsigned ph = ((unsigned)yh << 16) | xh;
            const unsigned pl = ((unsigned)yl << 16) | xl;
            bhI.u[3] = (q == 3) ? ((H16ONE << 16) | H16ONE)
                                : ((q == 1) ? pl : ph);
        }

        const v4f z = {0.f, 0.f, 0.f, 0.f};

        // int MFMAs (own job)
        const v4f E0 = __builtin_amdgcn_mfma_f32_16x16x32_f16(AI[0], bhI.h, z, 0, 0, 0);
        const v4f E1 = __builtin_amdgcn_mfma_f32_16x16x32_f16(AI[1], bhI.h, z, 0, 0, 0);

        // his MFMAs: job A then job B (my 4 gate-tiles each)
        v4f DA[4], DB[4];
#pragma unroll
        for (int Tl = 0; Tl < 4; ++Tl) {
            const v4f cx = __builtin_amdgcn_mfma_f32_16x16x32_f16(AX[Tl], bxA.h, z, 0, 0, 0);
            DA[Tl] = __builtin_amdgcn_mfma_f32_16x16x32_f16(AW[Tl], bhA.h, cx, 0, 0, 0);
        }
#pragma unroll
        for (int Tl = 0; Tl < 4; ++Tl) {
            const v4f cx = __builtin_amdgcn_mfma_f32_16x16x32_f16(AX[Tl], bxB.h, z, 0, 0, 0);
            DB[Tl] = __builtin_amdgcn_mfma_f32_16x16x32_f16(AW[Tl], bhB.h, cx, 0, 0, 0);
        }

        // int activations (own job)
        lstm_unit(E0[0], E0[2], E1[0], E1[2], cI0, ih0);
        lstm_unit(E0[1], E0[3], E1[1], E1[3], cI1, ih1);
        {
            const unsigned short hh0 = f2h(ih0), hh1 = f2h(ih1);
            const unsigned short hl0 = f2h(ih0 - h2f(hh0));
            const unsigned short hl1 = f2h(ih1 - h2f(hh1));
            bhI.u[0] = ((unsigned)hh1 << 16) | hh0;
            bhI.u[1] = bhI.u[0];
            bhI.u[2] = ((unsigned)hl1 << 16) | hl0;
        }

        // his activations A, write LDS; then B, write LDS
#pragma unroll
        for (int r = 0; r < 4; ++r)
            lstm_unit(DA[0][r], DA[1][r], DA[2][r], DA[3][r], cHA[r], hHA[r]);
        {
            const unsigned p0 = ((unsigned)f2h(hHA[1]) << 16) | f2h(hHA[0]);
            const unsigned p1 = ((unsigned)f2h(hHA[3]) << 16) | f2h(hHA[2]);
            *reinterpret_cast<uint2*>(&hb[s & 1][0][wb]) = make_uint2(p0, p1);
        }
#pragma unroll
        for (int r = 0; r < 4; ++r)
            lstm_unit(DB[0][r], DB[1][r], DB[2][r], DB[3][r], cHB[r], hHB[r]);
        {
            const unsigned p0 = ((unsigned)f2h(hHB[1]) << 16) | f2h(hHB[0]);
            const unsigned p1 = ((unsigned)f2h(hHB[3]) << 16) | f2h(hHB[2]);
            *reinterpret_cast<uint2*>(&hb[s & 1][1][wb]) = make_uint2(p0, p1);
        }

        // prefix readout partial (job A; 8/772 blocks, wave-uniform)
        float re0 = 0.f, re1 = 0.f;
        if (readout) {
            if (w == 0) {
                re0 = fmaf(W_out[33 + 2 * q], ih1, W_out[32 + 2 * q] * ih0);
                re1 = fmaf(W_out[73 + 2 * q], ih1, W_out[72 + 2 * q] * ih0);
            }
            his_partial(W_out, hHA, w * 16 + q * 4, re0, re1);
            re0 += __shfl_xor(re0, 16); re1 += __shfl_xor(re1, 16);
            re0 += __shfl_xor(re0, 32); re1 += __shfl_xor(re1, 32);
            if (w == 1 && lane < 16) {
                float2 p; p.x = re0; p.y = re1;
                ebuf[s & 1][n] = p;
            }
        }

        __syncthreads();

        {
            const uint4 rA = *reinterpret_cast<const uint4*>(&hb[s & 1][0][rb]);
            bhA.u[0] = rA.x; bhA.u[1] = rA.y; bhA.u[2] = rA.z; bhA.u[3] = rA.w;
            const uint4 rB = *reinterpret_cast<const uint4*>(&hb[s & 1][1][rb]);
            bhB.u[0] = rB.x; bhB.u[1] = rB.y; bhB.u[2] = rB.z; bhB.u[3] = rB.w;
        }

        if (readout && w == 0 && lane < 16) {
            const float2 p = ebuf[s & 1][n];
            float2 o;
            o.x = re0 + p.x + b_out[0];
            o.y = re1 + p.y + b_out[1];
            reinterpret_cast<float2*>(out)[s * 128 + chainA] = o;
        }

        xvHA = xnHA; xvHB = xnHB; xvI = xnI;
    }

    // ---- epilogue: A (full blocks) + B (always) -------------------------
    __syncthreads();   // protect ebuf against the last readout's pending read

    float eA0 = 0.f, eA1 = 0.f, eB0 = 0.f, eB1 = 0.f;
    if (w == 0) {      // intA lives in wave 0
        eA0 = fmaf(W_out[33 + 2 * q], ih1, W_out[32 + 2 * q] * ih0);
        eA1 = fmaf(W_out[73 + 2 * q], ih1, W_out[72 + 2 * q] * ih0);
    } else {           // intB lives in wave 1
        eB0 = fmaf(W_out[33 + 2 * q], ih1, W_out[32 + 2 * q] * ih0);
        eB1 = fmaf(W_out[73 + 2 * q], ih1, W_out[72 + 2 * q] * ih0);
    }
    his_partial(W_out, hHA, w * 16 + q * 4, eA0, eA1);
    his_partial(W_out, hHB, w * 16 + q * 4, eB0, eB1);
    eA0 += __shfl_xor(eA0, 16); eA1 += __shfl_xor(eA1, 16);
    eA0 += __shfl_xor(eA0, 32); eA1 += __shfl_xor(eA1, 32);
    eB0 += __shfl_xor(eB0, 16); eB1 += __shfl_xor(eB1, 16);
    eB0 += __shfl_xor(eB0, 32); eB1 += __shfl_xor(eB1, 32);

    if (w == 1 && lane < 16) {
        float2 pa; pa.x = eA0; pa.y = eA1;
        float2 pb; pb.x = eB0; pb.y = eB1;
        ebuf[0][n] = pa;
        ebuf[1][n] = pb;
    }
    __syncthreads();
    if (w == 0 && lane < 16) {
        if (!readout) {
            const float2 p = ebuf[0][n];
            float2 o;
            o.x = eA0 + p.x + b_out[0];
            o.y = eA1 + p.y + b_out[1];
            reinterpret_cast<float2*>(out)[(63 + jA) * 128 + chainA] = o;
        }
        const float2 p = ebuf[1][n];
        float2 o;
        o.x = eB0 + p.x + b_out[0];
        o.y = eB1 + p.y + b_out[1];
        reinterpret_cast<float2*>(out)[(63 + jB) * 128 + chainB] = o;
    }
}

extern "C" void kernel_launch(void* const* d_in, const int* in_sizes, int n_in,
                              void* d_out, int out_size, void* d_ws, size_t ws_size,
                              hipStream_t stream) {
    const float* inp     = (const float*)d_in[0];
    const float* Wih_his = (const float*)d_in[1];
    const float* Whh_his = (const float*)d_in[2];
    const float* bih_his = (const float*)d_in[3];
    const float* bhh_his = (const float*)d_in[4];
    const float* Wih_int = (const float*)d_in[5];
    const float* Whh_int = (const float*)d_in[6];
    const float* bih_int = (const float*)d_in[7];
    const float* bhh_int = (const float*)d_in[8];
    const float* W_out   = (const float*)d_in[9];
    const float* b_out   = (const float*)d_in[10];
    float* out  = (float*)d_out;
    float* ws   = (float*)d_ws;

    // pre-pass: build unit-split fp16 A-frag tables (hi/lo exact splits)
    prep_kernel<<<dim3(36), dim3(256), 0, stream>>>(
        Wih_his, Whh_his, bih_his, bhh_his,
        Wih_int, Whh_int, bih_int, bhh_int, ws);

    // fused his+int LSTM: 772 blocks x 2 waves; each wave = half-units of
    // TWO jobs (intra-wave ILP) -> 1544 waves, ~1.5/SIMD, duty ~0.66
    fusedq_kernel<<<dim3(772), dim3(128), 0, stream>>>(
        inp, ws, W_out, b_out, out);
}

// Round 20
// 175.389 us; speedup vs baseline: 1.0741x; 1.0741x over previous
//
#include <hip/hip_runtime.h>

// Trajectron sliding-window LSTM embed:
//   inputs [T=256, B=128, N=4, D=2] f32
//   his LSTM H=32 over n=3; int LSTM H=8 over n=0; window 64 ending at t
//   out[t,b,:] = [h_his | h_int] @ W_out.T + b_out   -> [256,128,2] f32
//
// Round-32 (FINAL = revert to R29, the session best: kernel 112.6us,
// total ~177us). R30/R31 completed the structural search matrix:
//   R29 1-wave/1-job balanced: port 0.56, 112.6us  <- BEST
//   R30 1-wave/2-job:          port 0.50, 125.7us (duty 0.66 but 0.75 w/SIMD)
//   R28 2-wave split balanced: port 0.54, 118.4us (barrier-coupled)
//   R31 2-wave split x 2-job:  port 0.57, 124.4us (barrier re-couples)
// Closed-form ceiling: 1544 independent 64-step serial jobs (prefix-sharing
// already extracted all window redundancy; LSTM is non-associative -> no
// scan). Max 1.5 waves/SIMD; 2-wave SIMDs already issue at 74% port and
// finish with the latency-bound 1-wave SIMDs: 64 steps x 4220 cy = 112.6us.
// Structure: 193 windows x 8 chain-groups = 1544 one-wave blocks, all
// exactly 64 steps, no LDS, no barrier, pure-register zero-transpose
// recurrence (lane(q,n) computes h-units q*8..+7 of chain n == its own
// next-step B-frag slots). j=0 blocks are prefix blocks (readout every
// step -> t=0..63). 18 MFMAs + ~70 trans per step; 7-trans lstm_unit.
// Numerics: verified absmax 4.88e-4 (threshold 2.75e-3).

typedef float v4f __attribute__((ext_vector_type(4)));
typedef _Float16 h8v __attribute__((ext_vector_type(8)));

static __device__ __forceinline__ float fexp2(float x) {
    return __builtin_amdgcn_exp2f(x);
}
static __device__ __forceinline__ float frcp(float x) {
    return __builtin_amdgcn_rcpf(x);
}
static __device__ __forceinline__ unsigned short f2h(float f) {
    _Float16 h = (_Float16)f;
    unsigned short u;
    __builtin_memcpy(&u, &h, 2);
    return u;
}
static __device__ __forceinline__ float h2f(unsigned short u) {
    _Float16 h;
    __builtin_memcpy(&h, &u, 2);
    return (float)h;
}

#define LOG2E    1.442695041f
#define TWOLOG2E 2.885390082f
#define H16ONE   0x3C00u

// 7-trans LSTM unit update (5 exp2 + 2 rcp).
// Inputs are prescaled gate pre-activations: Di=-i*log2e, Df=-f*log2e,
// Dg=-2g*log2e, Do=-o*log2e (from the MFMA). c,h updated in place.
static __device__ __forceinline__ void lstm_unit(
    float Di, float Df, float Dg, float Do, float& c, float& h)
{
    const float ei = fminf(fexp2(Di), 1e12f);
    const float ef = fminf(fexp2(Df), 1e12f);
    const float eg = fminf(fexp2(Dg), 1e12f);
    const float eo = fminf(fexp2(Do), 1e18f);
    const float pi1 = 1.f + ei, pf1 = 1.f + ef, pg1 = 1.f + eg;
    const float p12 = pi1 * pg1;                  // (1+ei)(1+eg)
    const float r3  = frcp(p12 * pf1);            // <= 1e36, no INF
    const float cn  = fmaf(p12, c, (1.f - eg) * pf1) * r3;
    c = cn;
    const float ec = fminf(fexp2(TWOLOG2E * cn), 1e18f);
    h = (ec - 1.f) * frcp((1.f + eo) * (1.f + ec));
}

// ws layout:
//   ushort [0,4096)     hisAW : A-frags WhhP his, [T=8][n=16][k=32]
//   ushort [4096,8192)  hisAX : A-frags x-part his (k<8 used), [8][16][32]
//   ushort [8192,9216)  intAW : A-frags int (Whh+Wih+b in K-slots), [2][16][32]
//
// his perm: row p = T*16 + m (m = A-row = D-row): gate g = T>>1,
//   unit u = (m>>2)*8 + 4*(T&1) + (m&3), orig = g*32+u
// int perm: row p = T*16 + m: gate g = 2T + ((m&3)>>1),
//   unit u = 2*(m>>2) + (m&1), orig = g*8+u
// scale s = -log2e (i,f,o gates) / -2log2e (g gate)
__global__ __launch_bounds__(256) void prep_kernel(
    const float* __restrict__ Wih_his, const float* __restrict__ Whh_his,
    const float* __restrict__ bih_his, const float* __restrict__ bhh_his,
    const float* __restrict__ Wih_int, const float* __restrict__ Whh_int,
    const float* __restrict__ bih_int, const float* __restrict__ bhh_int,
    float* __restrict__ ws)
{
    const int i = blockIdx.x * 256 + threadIdx.x;
    unsigned short* wsu = reinterpret_cast<unsigned short*>(ws);

    if (i < 4096) {                     // hisAW: Whh part
        const int T = i >> 9, m = (i >> 5) & 15, k = i & 31;
        const int g = T >> 1;
        const int u = ((m >> 2) << 3) + ((T & 1) << 2) + (m & 3);
        const int orig = g * 32 + u;
        const float s = (g == 2) ? -TWOLOG2E : -LOG2E;
        wsu[i] = f2h(Whh_his[orig * 32 + k] * s);
    } else if (i < 8192) {              // hisAX: x-part (hi/lo exact)
        const int e = i - 4096;
        const int T = e >> 9, m = (e >> 5) & 15, k = e & 31;
        const int g = T >> 1;
        const int u = ((m >> 2) << 3) + ((T & 1) << 2) + (m & 3);
        const int orig = g * 32 + u;
        const float s = (g == 2) ? -TWOLOG2E : -LOG2E;
        const float w0 = Wih_his[orig * 2] * s;
        const float w1 = Wih_his[orig * 2 + 1] * s;
        const float b  = (bih_his[orig] + bhh_his[orig]) * s;
        unsigned short v = 0;
        switch (k) {
            case 0: v = f2h(w0); break;
            case 1: v = f2h(w1); break;
            case 2: v = f2h(b);  break;
            case 3: v = f2h(w0 - h2f(f2h(w0))); break;
            case 4: v = f2h(w1 - h2f(f2h(w1))); break;
            case 5: v = f2h(b  - h2f(f2h(b)));  break;
            case 6: v = f2h(w0); break;
            case 7: v = f2h(w1); break;
            default: v = 0; break;
        }
        wsu[4096 + e] = v;
    } else if (i < 9216) {              // intAW: Whh + Wih + b in K-slots
        const int e = i - 8192;
        const int T = e >> 9, m = (e >> 5) & 15, k = e & 31;
        const int q = k >> 3, j = k & 7;
        const int g = 2 * T + ((m & 3) >> 1);
        const int u = 2 * (m >> 2) + (m & 1);
        const int orig = g * 8 + u;
        const float s = (g == 2) ? -TWOLOG2E : -LOG2E;
        unsigned short v = 0;
        if (j < 6) {
            const int col = 2 * q + (j & 1);
            const float w = Whh_int[orig * 8 + col] * s;
            v = (j == 2 || j == 3) ? f2h(w - h2f(f2h(w))) : f2h(w);
        } else {
            const int comp = j & 1;
            if (q <= 1) {                       // w_hi . xh / w_hi . xl
                v = f2h(Wih_int[orig * 2 + comp] * s);
            } else if (q == 2) {                // w_lo . xh
                const float w = Wih_int[orig * 2 + comp] * s;
                v = f2h(w - h2f(f2h(w)));
            } else {                            // bias hi / lo
                const float b = (bih_int[orig] + bhh_int[orig]) * s;
                v = (comp == 0) ? f2h(b) : f2h(b - h2f(f2h(b)));
            }
        }
        wsu[8192 + e] = v;
    }
}

// ---------- fused his+int LSTM: 1 wave/block, 16 chains, balanced --------
// Block Wd: j = Wd>>3 (0..192), bg = Wd&7. tau0 = j; 64 steps always.
//   j == 0 : prefix block -- h after step s IS output t=s (in-loop readout)
//   j >= 1 : window [j, j+63], output t = 63+j at the end.
__global__ __launch_bounds__(64) void fusedw_kernel(
    const float* __restrict__ inp, const float* __restrict__ ws,
    const float* __restrict__ W_out, const float* __restrict__ b_out,
    float* __restrict__ out)
{
    const int lane = threadIdx.x;
    const int n    = lane & 15;
    const int q    = lane >> 4;
    const int Wd   = blockIdx.x;               // 0..1543
    const int j    = Wd >> 3;                  // 0..192
    const int bg   = Wd & 7;
    const int tau0 = j;
    const bool readout = (j == 0);             // wave-uniform

    const unsigned short* wsu = reinterpret_cast<const unsigned short*>(ws);
    const h8v* wa = reinterpret_cast<const h8v*>(wsu);          // hisAW
    const h8v* wx = reinterpret_cast<const h8v*>(wsu + 4096);   // hisAX
    const h8v* wi = reinterpret_cast<const h8v*>(wsu + 8192);   // intAW
    h8v AW[8], AX[8], AI[2];
#pragma unroll
    for (int T = 0; T < 8; ++T) {
        AW[T] = wa[T * 64 + n * 4 + q];
        AX[T] = wx[T * 64 + n * 4 + q];
    }
#pragma unroll
    for (int T = 0; T < 2; ++T) AI[T] = wi[T * 64 + n * 4 + q];

    // projection weights, hoisted (his units q*8..+7; int units {2q,2q+1})
    const v4f w0a = *reinterpret_cast<const v4f*>(W_out + q * 8);
    const v4f w0b = *reinterpret_cast<const v4f*>(W_out + q * 8 + 4);
    const v4f w1a = *reinterpret_cast<const v4f*>(W_out + 40 + q * 8);
    const v4f w1b = *reinterpret_cast<const v4f*>(W_out + 40 + q * 8 + 4);
    const float wi0a = W_out[32 + 2 * q], wi0b = W_out[33 + 2 * q];
    const float wi1a = W_out[72 + 2 * q], wi1b = W_out[73 + 2 * q];
    const float bo0 = b_out[0], bo1 = b_out[1];

    const int chain = bg * 16 + n;
    const float* xb0 = inp + chain * 8;
    float2 xvH = *reinterpret_cast<const float2*>(xb0 + tau0 * 1024 + 6);
    float2 xvI = *reinterpret_cast<const float2*>(xb0 + tau0 * 1024);

    union BU { unsigned u[4]; h8v h; };
    BU bhH; bhH.u[0] = bhH.u[1] = bhH.u[2] = bhH.u[3] = 0;   // his h
    BU bhI; bhI.u[0] = bhI.u[1] = bhI.u[2] = bhI.u[3] = 0;   // int h
    float cH[8] = {0.f, 0.f, 0.f, 0.f, 0.f, 0.f, 0.f, 0.f};
    float hH[8] = {0.f, 0.f, 0.f, 0.f, 0.f, 0.f, 0.f, 0.f};
    float cI0 = 0.f, cI1 = 0.f, ih0 = 0.f, ih1 = 0.f;

#pragma unroll 1
    for (int s = 0; s < 64; ++s) {
        // branch-free prefetch (last iteration's value is dead; row <= 255)
        const int sn = (s < 63) ? (s + 1) : 63;
        const float* xr = xb0 + (tau0 + sn) * 1024;
        const float2 xnH = *reinterpret_cast<const float2*>(xr + 6);
        const float2 xnI = *reinterpret_cast<const float2*>(xr);

        // his Bx: q0 lanes carry [xh, yh, 1, xh, yh, 1, xl, yl]; others 0
        BU bx;
        {
            const unsigned short xh = f2h(xvH.x), yh = f2h(xvH.y);
            const unsigned short xl = f2h(xvH.x - h2f(xh));
            const unsigned short yl = f2h(xvH.y - h2f(yh));
            bx.u[0] = ((unsigned)yh << 16) | xh;             // j1,j0
            bx.u[1] = ((unsigned)xh << 16) | H16ONE;         // j3=xh, j2=1
            bx.u[2] = (H16ONE << 16) | yh;                   // j5=1, j4=yh
            bx.u[3] = ((unsigned)yl << 16) | xl;             // j7,j6
            if (q != 0) { bx.u[0] = 0; bx.u[1] = 0; bx.u[2] = 0; bx.u[3] = 0; }
        }
        // int B x-slot: q0/q2 -> (xh,yh); q1 -> (xl,yl); q3 -> (1,1)
        {
            const unsigned short xh = f2h(xvI.x), yh = f2h(xvI.y);
            const unsigned short xl = f2h(xvI.x - h2f(xh));
            const unsigned short yl = f2h(xvI.y - h2f(yh));
            const unsigned ph = ((unsigned)yh << 16) | xh;
            const unsigned pl = ((unsigned)yl << 16) | xl;
            bhI.u[3] = (q == 3) ? ((H16ONE << 16) | H16ONE)
                                : ((q == 1) ? pl : ph);
        }

        const v4f z = {0.f, 0.f, 0.f, 0.f};

        // int: 2 MFMAs (fully independent of his chain)
        const v4f E0 = __builtin_amdgcn_mfma_f32_16x16x32_f16(AI[0], bhI.h, z, 0, 0, 0);
        const v4f E1 = __builtin_amdgcn_mfma_f32_16x16x32_f16(AI[1], bhI.h, z, 0, 0, 0);

        // his: 16 MFMAs D[T] = WhhP_T . h + WihP_T . [x;1]
        v4f D[8];
#pragma unroll
        for (int T = 0; T < 8; ++T) {
            const v4f cx = __builtin_amdgcn_mfma_f32_16x16x32_f16(AX[T], bx.h, z, 0, 0, 0);
            D[T] = __builtin_amdgcn_mfma_f32_16x16x32_f16(AW[T], bhH.h, cx, 0, 0, 0);
        }

        // int activations: units {2q, 2q+1} of chain n (7-trans form)
        lstm_unit(E0[0], E0[2], E1[0], E1[2], cI0, ih0);
        lstm_unit(E0[1], E0[3], E1[1], E1[3], cI1, ih1);

        // int h -> B-frag, in-lane (hi/lo corrected, rte-exact)
        {
            const unsigned short hh0 = f2h(ih0), hh1 = f2h(ih1);
            const unsigned short hl0 = f2h(ih0 - h2f(hh0));
            const unsigned short hl1 = f2h(ih1 - h2f(hh1));
            bhI.u[0] = ((unsigned)hh1 << 16) | hh0;
            bhI.u[1] = bhI.u[0];
            bhI.u[2] = ((unsigned)hl1 << 16) | hl0;
        }

        // his activations: 8 units (q*8+ww) of chain n (7-trans form)
#pragma unroll
        for (int hi = 0; hi < 2; ++hi) {
#pragma unroll
            for (int lo = 0; lo < 4; ++lo) {
                const int ww = hi * 4 + lo;
                lstm_unit(D[hi][lo], D[2 + hi][lo], D[4 + hi][lo],
                          D[6 + hi][lo], cH[ww], hH[ww]);
            }
        }
        // his h -> B-frag, in-lane (uncorrected: keep verified rte f2h)
#pragma unroll
        for (int d = 0; d < 4; ++d)
            bhH.u[d] = ((unsigned)f2h(hH[2 * d + 1]) << 16) | f2h(hH[2 * d]);

        // prefix-block readout: h after step s == output t=s (8/1544 blocks)
        if (readout) {
            float e0 = fmaf(wi0b, ih1, wi0a * ih0);
            float e1 = fmaf(wi1b, ih1, wi1a * ih0);
#pragma unroll
            for (int jj = 0; jj < 4; ++jj) {
                e0 = fmaf(w0a[jj], hH[jj], fmaf(w0b[jj], hH[4 + jj], e0));
                e1 = fmaf(w1a[jj], hH[jj], fmaf(w1b[jj], hH[4 + jj], e1));
            }
            e0 += __shfl_xor(e0, 16); e1 += __shfl_xor(e1, 16);
            e0 += __shfl_xor(e0, 32); e1 += __shfl_xor(e1, 32);
            if (lane < 16) {
                float2 o;
                o.x = e0 + bo0;
                o.y = e1 + bo1;
                reinterpret_cast<float2*>(out)[s * 128 + chain] = o;
            }
        }

        xvH = xnH;
        xvI = xnI;
    }

    // ---- epilogue (full blocks only): output t = 63 + j -----------------
    if (!readout) {
        float e0 = fmaf(wi0b, ih1, wi0a * ih0);
        float e1 = fmaf(wi1b, ih1, wi1a * ih0);
#pragma unroll
        for (int jj = 0; jj < 4; ++jj) {
            e0 = fmaf(w0a[jj], hH[jj], fmaf(w0b[jj], hH[4 + jj], e0));
            e1 = fmaf(w1a[jj], hH[jj], fmaf(w1b[jj], hH[4 + jj], e1));
        }
        e0 += __shfl_xor(e0, 16); e1 += __shfl_xor(e1, 16);
        e0 += __shfl_xor(e0, 32); e1 += __shfl_xor(e1, 32);

        if (lane < 16) {
            float2 o;
            o.x = e0 + bo0;
            o.y = e1 + bo1;
            reinterpret_cast<float2*>(out)[(63 + j) * 128 + chain] = o;
        }
    }
}

extern "C" void kernel_launch(void* const* d_in, const int* in_sizes, int n_in,
                              void* d_out, int out_size, void* d_ws, size_t ws_size,
                              hipStream_t stream) {
    const float* inp     = (const float*)d_in[0];
    const float* Wih_his = (const float*)d_in[1];
    const float* Whh_his = (const float*)d_in[2];
    const float* bih_his = (const float*)d_in[3];
    const float* bhh_his = (const float*)d_in[4];
    const float* Wih_int = (const float*)d_in[5];
    const float* Whh_int = (const float*)d_in[6];
    const float* bih_int = (const float*)d_in[7];
    const float* bhh_int = (const float*)d_in[8];
    const float* W_out   = (const float*)d_in[9];
    const float* b_out   = (const float*)d_in[10];
    float* out  = (float*)d_out;
    float* ws   = (float*)d_ws;

    // pre-pass: build permuted fp16 A-frag tables (hi/lo exact splits)
    prep_kernel<<<dim3(36), dim3(256), 0, stream>>>(
        Wih_his, Whh_his, bih_his, bhh_his,
        Wih_int, Whh_int, bih_int, bhh_int, ws);

    // fused his+int LSTM: 1544 balanced 1-wave blocks (prefix-sharing),
    // no LDS, no barrier -- independent waves decorrelate stalls
    fusedw_kernel<<<dim3(1544), dim3(64), 0, stream>>>(
        inp, ws, W_out, b_out, out);
}